// Round 3
// baseline (523.577 us; speedup 1.0000x reference)
//
#include <hip/hip_runtime.h>
#include <hip/hip_bf16.h>
#include <stdint.h>

#define QL 1024
#define KL 1024
#define HM 64
#define DD 128
#define SM_SCALE 0.08838834764831845f

typedef __bf16 bf16x8 __attribute__((ext_vector_type(8)));
typedef float floatx4 __attribute__((ext_vector_type(4)));
// 4-byte-aligned float4 for the (q*1025 + k) strided output rows
typedef float floatx4u __attribute__((ext_vector_type(4), aligned(4)));

// =====================================================================
// qk4: zero-LDS, zero-barrier streaming kernel.
//   One block per (g, qt); 4 independent waves, each 64q x 32k per K-tile.
//   - Q fragments (64 rows x 128 d per wave) held in registers the whole
//     kernel: 16 x bf16x8 = 64 VGPR, loaded once (fp32 -> bf16).
//   - K fragments loaded global->reg->cvt per 64-row tile. No K-reuse
//     inside a wave, so LDS buys nothing but barriers: deleted.
//   - No __syncthreads anywhere -> epilogue stores are NEVER drained
//     (no implicit vmcnt(0)); compiler pipelines loads across iterations.
//   - Nontemporal output stores: 269 MB write stream bypasses L2 so the
//     mask + K working set (~8 MB/XCD) stops thrashing the 4 MB L2.
//   - XCD-chunked bid mapping: bid&7 = XCD; 8 qt-blocks of the same g on
//     one XCD share K slices via L2; mask rows shared across g.
//   - sink column fused.
// =====================================================================
__global__ __launch_bounds__(256, 2)
void qk4_kernel(const float* __restrict__ Qg, const float* __restrict__ Kg,
                const float* __restrict__ mask, const float* __restrict__ sinks,
                float* __restrict__ out)
{
    const int bid   = blockIdx.x;      // 0..511
    const int xcd   = bid & 7;
    const int inner = bid >> 3;        // 0..63
    const int qt    = inner & 7;
    const int g     = xcd * 8 + (inner >> 3);

    const int t    = threadIdx.x;
    const int wave = t >> 6;
    const int lane = t & 63;
    const int wm   = (wave & 1) * 64;  // q offset within 128-tile
    const int wnk  = (wave >> 1) * 32; // k offset within 64-subtile
    const int lr   = lane & 15;
    const int quad = lane >> 4;

    // ---- Q fragments -> registers (held for entire kernel) ----
    // af[ks][mi]: row = qt*128 + wm + mi*16 + lr, d = ks*32 + quad*8 .. +7
    bf16x8 af[4][4];
    {
        const float* Qb = Qg + ((size_t)(qt * 128 + wm + lr) * HM + g) * DD + quad * 8;
#pragma unroll
        for (int mi = 0; mi < 4; ++mi) {
            const float* qr = Qb + (size_t)mi * 16 * HM * DD;
#pragma unroll
            for (int ks = 0; ks < 4; ++ks) {
                float4 a = *(const float4*)(qr + ks * 32);
                float4 b = *(const float4*)(qr + ks * 32 + 4);
                af[ks][mi] = (bf16x8){ (__bf16)a.x, (__bf16)a.y, (__bf16)a.z, (__bf16)a.w,
                                       (__bf16)b.x, (__bf16)b.y, (__bf16)b.z, (__bf16)b.w };
            }
        }
    }

    const size_t obase = (size_t)g * QL * 1025;
    const float* Kb0 = Kg + ((size_t)(wnk + lr) * HM + g) * DD + quad * 8;

    for (int kt = 0; kt < 16; ++kt) {
        // ---- K fragments global->reg, fp32->bf16 ----
        // bfr[ks][ni]: row = kt*64 + wnk + ni*16 + lr, d = ks*32 + quad*8
        const float* Kb = Kb0 + (size_t)(kt * 64) * (HM * DD);
        bf16x8 bfr[4][2];
#pragma unroll
        for (int ni = 0; ni < 2; ++ni) {
            const float* kr = Kb + (size_t)ni * 16 * (HM * DD);
#pragma unroll
            for (int ks = 0; ks < 4; ++ks) {
                float4 x = *(const float4*)(kr + ks * 32);
                float4 y = *(const float4*)(kr + ks * 32 + 4);
                bfr[ks][ni] = (bf16x8){ (__bf16)x.x, (__bf16)x.y, (__bf16)x.z, (__bf16)x.w,
                                        (__bf16)y.x, (__bf16)y.y, (__bf16)y.z, (__bf16)y.w };
            }
        }

        // ---- MFMA: swapped operands mfma(K, Q) ----
        floatx4 acc[4][2] = {};
#pragma unroll
        for (int ks = 0; ks < 4; ++ks)
#pragma unroll
            for (int mi = 0; mi < 4; ++mi)
#pragma unroll
                for (int ni = 0; ni < 2; ++ni)
                    acc[mi][ni] = __builtin_amdgcn_mfma_f32_16x16x32_bf16(
                        bfr[ks][ni], af[ks][mi], acc[mi][ni], 0, 0, 0);

        // ---- epilogue: col=lane&15 -> q, row=quad*4+r -> k (swapped) ----
#pragma unroll
        for (int mi = 0; mi < 4; ++mi) {
            const int q = (qt << 7) + wm + mi * 16 + lr;
            const float* mrow = mask + ((size_t)q << 10);
            float* orow = out + obase + (size_t)q * 1025;
#pragma unroll
            for (int ni = 0; ni < 2; ++ni) {
                const int k0 = (kt << 6) + wnk + ni * 16 + (quad << 2);
                floatx4 mv = *(const floatx4*)(mrow + k0);       // 16B aligned
                floatx4 v  = acc[mi][ni] * SM_SCALE + mv;
                __builtin_nontemporal_store(v, (floatx4u*)(orow + k0)); // dwordx4, nt
            }
        }
    }

    // ---- fused sink column ----
    if (t < 128) {
        const int q = (qt << 7) + t;
        out[obase + (size_t)q * 1025 + 1024] = sinks[((size_t)g << 10) + q];
    }
}

extern "C" void kernel_launch(void* const* d_in, const int* in_sizes, int n_in,
                              void* d_out, int out_size, void* d_ws, size_t ws_size,
                              hipStream_t stream)
{
    const float* Q     = (const float*)d_in[0];
    const float* K     = (const float*)d_in[1];
    const float* mask  = (const float*)d_in[2];
    const float* sinks = (const float*)d_in[3];
    float* out = (float*)d_out;

    qk4_kernel<<<512, 256, 0, stream>>>(Q, K, mask, sinks, out);
}

// Round 4
// 508.110 us; speedup vs baseline: 1.0304x; 1.0304x over previous
//
#include <hip/hip_runtime.h>
#include <hip/hip_bf16.h>
#include <stdint.h>

#define QL 1024
#define KL 1024
#define HM 64
#define DD 128
#define SM_SCALE 0.08838834764831845f

typedef __bf16 bf16x8 __attribute__((ext_vector_type(8)));
typedef float floatx4 __attribute__((ext_vector_type(4)));
// 4-byte-aligned float4 for the (q*1025 + k) strided output rows
typedef float floatx4u __attribute__((ext_vector_type(4), aligned(4)));

// =====================================================================
// qk5: zero-LDS, zero-barrier streaming kernel, CACHED stores.
//   One block per (g, qt); 4 independent waves, each 64q x 32k per K-tile.
//   - Q fragments (64 rows x 128 d per wave) held in registers the whole
//     kernel, loaded once (fp32 -> bf16).
//   - K fragments loaded global->reg->cvt per 64-row tile. No K-reuse
//     inside a wave, so LDS buys nothing but barriers: deleted.
//   - No __syncthreads anywhere -> epilogue stores are NEVER drained
//     (no implicit vmcnt(0)); loads for iter kt+1 overlap stores of kt.
//   - REGULAR float4 stores (qk4 post-mortem): the 4100B-strided rows
//     NEED the L2 write-back path to merge 16B stores into full lines.
//     NT stores bypassed L2 -> 1.43x HBM write amplification (RMW on
//     partial sectors) and a latency wall: 283 us, 17% BW. Reverted.
//   - XCD-chunked bid mapping: bid&7 = XCD; 8 qt-blocks of the same g on
//     one XCD share K slices via L2; mask rows shared across qt-peers.
//   - sink column fused.
// =====================================================================
__global__ __launch_bounds__(256, 2)
void qk5_kernel(const float* __restrict__ Qg, const float* __restrict__ Kg,
                const float* __restrict__ mask, const float* __restrict__ sinks,
                float* __restrict__ out)
{
    const int bid   = blockIdx.x;      // 0..511
    const int xcd   = bid & 7;
    const int inner = bid >> 3;        // 0..63
    const int qt    = inner & 7;
    const int g     = xcd * 8 + (inner >> 3);

    const int t    = threadIdx.x;
    const int wave = t >> 6;
    const int lane = t & 63;
    const int wm   = (wave & 1) * 64;  // q offset within 128-tile
    const int wnk  = (wave >> 1) * 32; // k offset within 64-subtile
    const int lr   = lane & 15;
    const int quad = lane >> 4;

    // ---- Q fragments -> registers (held for entire kernel) ----
    // af[ks][mi]: row = qt*128 + wm + mi*16 + lr, d = ks*32 + quad*8 .. +7
    bf16x8 af[4][4];
    {
        const float* Qb = Qg + ((size_t)(qt * 128 + wm + lr) * HM + g) * DD + quad * 8;
#pragma unroll
        for (int mi = 0; mi < 4; ++mi) {
            const float* qr = Qb + (size_t)mi * 16 * HM * DD;
#pragma unroll
            for (int ks = 0; ks < 4; ++ks) {
                float4 a = *(const float4*)(qr + ks * 32);
                float4 b = *(const float4*)(qr + ks * 32 + 4);
                af[ks][mi] = (bf16x8){ (__bf16)a.x, (__bf16)a.y, (__bf16)a.z, (__bf16)a.w,
                                       (__bf16)b.x, (__bf16)b.y, (__bf16)b.z, (__bf16)b.w };
            }
        }
    }

    const size_t obase = (size_t)g * QL * 1025;
    const float* Kb0 = Kg + ((size_t)(wnk + lr) * HM + g) * DD + quad * 8;

    for (int kt = 0; kt < 16; ++kt) {
        // ---- K fragments global->reg, fp32->bf16 ----
        // bfr[ks][ni]: row = kt*64 + wnk + ni*16 + lr, d = ks*32 + quad*8
        const float* Kb = Kb0 + (size_t)(kt * 64) * (HM * DD);
        bf16x8 bfr[4][2];
#pragma unroll
        for (int ni = 0; ni < 2; ++ni) {
            const float* kr = Kb + (size_t)ni * 16 * (HM * DD);
#pragma unroll
            for (int ks = 0; ks < 4; ++ks) {
                float4 x = *(const float4*)(kr + ks * 32);
                float4 y = *(const float4*)(kr + ks * 32 + 4);
                bfr[ks][ni] = (bf16x8){ (__bf16)x.x, (__bf16)x.y, (__bf16)x.z, (__bf16)x.w,
                                        (__bf16)y.x, (__bf16)y.y, (__bf16)y.z, (__bf16)y.w };
            }
        }

        // ---- MFMA: swapped operands mfma(K, Q) ----
        floatx4 acc[4][2] = {};
#pragma unroll
        for (int ks = 0; ks < 4; ++ks)
#pragma unroll
            for (int mi = 0; mi < 4; ++mi)
#pragma unroll
                for (int ni = 0; ni < 2; ++ni)
                    acc[mi][ni] = __builtin_amdgcn_mfma_f32_16x16x32_bf16(
                        bfr[ks][ni], af[ks][mi], acc[mi][ni], 0, 0, 0);

        // ---- epilogue: col=lane&15 -> q, row=quad*4+r -> k (swapped) ----
#pragma unroll
        for (int mi = 0; mi < 4; ++mi) {
            const int q = (qt << 7) + wm + mi * 16 + lr;
            const float* mrow = mask + ((size_t)q << 10);
            float* orow = out + obase + (size_t)q * 1025;
#pragma unroll
            for (int ni = 0; ni < 2; ++ni) {
                const int k0 = (kt << 6) + wnk + ni * 16 + (quad << 2);
                floatx4 mv = *(const floatx4*)(mrow + k0);       // 16B aligned
                floatx4 v  = acc[mi][ni] * SM_SCALE + mv;
                *(floatx4u*)(orow + k0) = v;                     // cached dwordx4
            }
        }
    }

    // ---- fused sink column ----
    if (t < 128) {
        const int q = (qt << 7) + t;
        out[obase + (size_t)q * 1025 + 1024] = sinks[((size_t)g << 10) + q];
    }
}

extern "C" void kernel_launch(void* const* d_in, const int* in_sizes, int n_in,
                              void* d_out, int out_size, void* d_ws, size_t ws_size,
                              hipStream_t stream)
{
    const float* Q     = (const float*)d_in[0];
    const float* K     = (const float*)d_in[1];
    const float* mask  = (const float*)d_in[2];
    const float* sinks = (const float*)d_in[3];
    float* out = (float*)d_out;

    qk5_kernel<<<512, 256, 0, stream>>>(Q, K, mask, sinks, out);
}

// Round 5
// 398.706 us; speedup vs baseline: 1.3132x; 1.2744x over previous
//
#include <hip/hip_runtime.h>
#include <hip/hip_bf16.h>
#include <stdint.h>

#define QL 1024
#define KL 1024
#define HM 64
#define DD 128
#define SM_SCALE 0.08838834764831845f
#define LDP 136   // bf16 row stride for Ks: 272B rows, 4-way max on frag reads
#define OSP 68    // f32 row stride for Os: 272B rows, 4-way max

typedef __bf16 bf16x8 __attribute__((ext_vector_type(8)));
typedef __bf16 bf16x4 __attribute__((ext_vector_type(4)));
typedef float floatx4 __attribute__((ext_vector_type(4)));
typedef float floatx4u __attribute__((ext_vector_type(4), aligned(4)));

// =====================================================================
// qk6: every global stream coalesced.
//   Block = (g, qt): 128 q rows. 4 waves x 32 q rows. 16 iters of 64 k.
//   - Q in registers for whole kernel (scattered load ONCE, negligible).
//   - K: cooperative coalesced staging -> double-buffered LDS, loads for
//     kt+1 issued at top of iter (hidden under MFMA), 1 barrier/iter.
//     (qk5 post-mortem: direct K frag loads are 16-segment gathers ->
//      latency wall at 3.5% VALUBusy; LDS staging is 512B segments.)
//   - Output+mask: accs go through a WAVE-PRIVATE LDS tile (no barrier),
//     read back flat so each mask-load/fma/store instruction covers
//     4 rows x 256 B contiguous instead of 16 scattered 64 B segments.
//   - Cached stores (qk4 post-mortem: NT stores -> 1.43x write ampl).
//   - XCD-chunked bid map; sink column fused.
// =====================================================================
__global__ __launch_bounds__(256, 2)
void qk6_kernel(const float* __restrict__ Qg, const float* __restrict__ Kg,
                const float* __restrict__ mask, const float* __restrict__ sinks,
                float* __restrict__ out)
{
    const int bid   = blockIdx.x;      // 0..511
    const int xcd   = bid & 7;
    const int inner = bid >> 3;        // 0..63
    const int qt    = inner & 7;
    const int g     = xcd * 8 + (inner >> 3);

    __shared__ __bf16 Ks[2][64][LDP];  // 34 KB
    __shared__ float  Os[4][32][OSP];  // 34 KB, wave-private slices

    const int t    = threadIdx.x;
    const int wave = t >> 6;
    const int lane = t & 63;
    const int lr   = lane & 15;
    const int quad = lane >> 4;
    const int wm   = wave * 32;        // q offset of wave within 128-tile

    // ---- Q fragments -> registers, held all kernel ----
    // af[ks][mi]: q = qt*128 + wm + mi*16 + lr, d = ks*32 + quad*8 .. +7
    bf16x8 af[4][2];
    {
        const float* Qb = Qg + ((size_t)(qt * 128 + wm + lr) * HM + g) * DD + quad * 8;
#pragma unroll
        for (int mi = 0; mi < 2; ++mi) {
            const float* qr = Qb + (size_t)mi * 16 * HM * DD;
#pragma unroll
            for (int ks = 0; ks < 4; ++ks) {
                float4 a = *(const float4*)(qr + ks * 32);
                float4 b = *(const float4*)(qr + ks * 32 + 4);
                af[ks][mi] = (bf16x8){ (__bf16)a.x, (__bf16)a.y, (__bf16)a.z, (__bf16)a.w,
                                       (__bf16)b.x, (__bf16)b.y, (__bf16)b.z, (__bf16)b.w };
            }
        }
    }

    // ---- stage K tile 0 (coalesced: 2 rows x 512 B per instruction) ----
    const float* Kbase = Kg + (size_t)g * DD;
#pragma unroll
    for (int j = 0; j < 8; ++j) {
        int c = t + 256 * j;           // 0..2047
        int row = c >> 5, c4 = c & 31;
        float4 b = *(const float4*)(Kbase + (size_t)row * (HM * DD) + c4 * 4);
        bf16x4 bv = { (__bf16)b.x, (__bf16)b.y, (__bf16)b.z, (__bf16)b.w };
        *(bf16x4*)&Ks[0][row][c4 * 4] = bv;
    }
    __syncthreads();

    const size_t obase = (size_t)g * QL * 1025;

    for (int kt = 0; kt < 16; ++kt) {
        const int b = kt & 1;

        // ---- issue next K tile loads early (hide under MFMA+epilogue) ----
        float4 nf[8];
        if (kt < 15) {
            const float* nb = Kg + (size_t)((kt + 1) * 64) * (HM * DD) + (size_t)g * DD;
#pragma unroll
            for (int j = 0; j < 8; ++j) {
                int c = t + 256 * j;
                nf[j] = *(const float4*)(nb + (size_t)(c >> 5) * (HM * DD) + (c & 31) * 4);
            }
        }

        // ---- MFMA: wave computes 32q x 64k, swapped operands mfma(K,Q) ----
        floatx4 acc[2][4] = {};
#pragma unroll
        for (int ks = 0; ks < 4; ++ks) {
            const int d0 = ks * 32 + quad * 8;
            bf16x8 kf[4];
#pragma unroll
            for (int ni = 0; ni < 4; ++ni)
                kf[ni] = *(const bf16x8*)&Ks[b][ni * 16 + lr][d0];
#pragma unroll
            for (int mi = 0; mi < 2; ++mi)
#pragma unroll
                for (int ni = 0; ni < 4; ++ni)
                    acc[mi][ni] = __builtin_amdgcn_mfma_f32_16x16x32_bf16(
                        kf[ni], af[ks][mi], acc[mi][ni], 0, 0, 0);
        }

        // ---- park accs in wave-private LDS tile (no barrier needed) ----
        // layout: col=lane&15 -> q(lr), row=quad*4+r -> k
#pragma unroll
        for (int mi = 0; mi < 2; ++mi)
#pragma unroll
            for (int ni = 0; ni < 4; ++ni)
                *(floatx4*)&Os[wave][mi * 16 + lr][ni * 16 + quad * 4] = acc[mi][ni];

        // ---- readback flat: 4 rows x 256 B contiguous per instruction ----
#pragma unroll
        for (int j = 0; j < 8; ++j) {
            int c = lane + 64 * j;         // 0..511
            int row = c >> 4, col = (c & 15) * 4;
            floatx4 v = *(const floatx4*)&Os[wave][row][col];
            const int q = (qt << 7) + wm + row;
            const int k0 = (kt << 6) + col;
            floatx4 mv = *(const floatx4*)(mask + ((size_t)q << 10) + k0);
            v = v * SM_SCALE + mv;
            *(floatx4u*)(out + obase + (size_t)q * 1025 + k0) = v;
        }

        // ---- convert + write next K tile, one barrier per iteration ----
        if (kt < 15) {
#pragma unroll
            for (int j = 0; j < 8; ++j) {
                int c = t + 256 * j;
                bf16x4 bv = { (__bf16)nf[j].x, (__bf16)nf[j].y,
                              (__bf16)nf[j].z, (__bf16)nf[j].w };
                *(bf16x4*)&Ks[1 - b][c >> 5][(c & 31) * 4] = bv;
            }
            __syncthreads();
        }
    }

    // ---- fused sink column ----
    if (t < 128) {
        const int q = (qt << 7) + t;
        out[obase + (size_t)q * 1025 + 1024] = sinks[((size_t)g << 10) + q];
    }
}

extern "C" void kernel_launch(void* const* d_in, const int* in_sizes, int n_in,
                              void* d_out, int out_size, void* d_ws, size_t ws_size,
                              hipStream_t stream)
{
    const float* Q     = (const float*)d_in[0];
    const float* K     = (const float*)d_in[1];
    const float* mask  = (const float*)d_in[2];
    const float* sinks = (const float*)d_in[3];
    float* out = (float*)d_out;

    qk6_kernel<<<512, 256, 0, stream>>>(Q, K, mask, sinks, out);
}